// Round 8
// baseline (1008.825 us; speedup 1.0000x reference)
//
#include <hip/hip_runtime.h>
#include <hip/hip_cooperative_groups.h>
#include <math.h>

namespace cg = cooperative_groups;

typedef short bf8 __attribute__((ext_vector_type(8)));   // 8 bf16 = 4 VGPRs
typedef float f4 __attribute__((ext_vector_type(4)));

__device__ inline unsigned short f2bf(float f) {          // RNE f32 -> bf16
    unsigned int u = __float_as_uint(f);
    u = u + 0x7fffu + ((u >> 16) & 1u);
    return (unsigned short)(u >> 16);
}
__device__ inline float bf2f(unsigned short h) {
    return __uint_as_float(((unsigned int)h) << 16);
}
__device__ inline void split_bf(float v, unsigned short& h, unsigned short& l) {
    h = f2bf(v);
    l = f2bf(v - bf2f(h));
}
__device__ inline unsigned int packbf(unsigned short a, unsigned short b) {
    return (unsigned int)a | ((unsigned int)b << 16);
}
__device__ inline void async16(const void* g, void* l) {
    __builtin_amdgcn_global_load_lds(
        (const __attribute__((address_space(1))) unsigned int*)g,
        (__attribute__((address_space(3))) unsigned int*)l, 16, 0, 0);
}

// ---------- fuse row-mean + center + bf16 hi/lo split (K padded 784->800 with zeros) ----------
__global__ __launch_bounds__(256) void center_convert(const float* __restrict__ x,
        unsigned short* __restrict__ Xh, unsigned short* __restrict__ Xl) {
    int row = blockIdx.x;                       // b*512 + c
    const float* xr = x + (size_t)row * 784;
    int t = threadIdx.x;
    float4 vv = {0.f, 0.f, 0.f, 0.f};
    if (t < 196) vv = *(const float4*)(xr + t * 4);
    float s = vv.x + vv.y + vv.z + vv.w;
    #pragma unroll
    for (int o = 32; o > 0; o >>= 1) s += __shfl_down(s, o, 64);
    __shared__ float red[4];
    int lane = t & 63, wv = t >> 6;
    if (lane == 0) red[wv] = s;
    __syncthreads();
    float m = (red[0] + red[1] + red[2] + red[3]) * (1.0f / 784.0f);
    if (t < 200) {
        ushort4 hh = {0, 0, 0, 0}, ll = {0, 0, 0, 0};
        if (t < 196) {
            split_bf(vv.x - m, hh.x, ll.x);
            split_bf(vv.y - m, hh.y, ll.y);
            split_bf(vv.z - m, hh.z, ll.z);
            split_bf(vv.w - m, hh.w, ll.w);
        }
        *(ushort4*)&Xh[(size_t)row * 800 + t * 4] = hh;
        *(ushort4*)&Xl[(size_t)row * 800 + t * 4] = ll;
    }
}

// ---------- full-grid bf16x3 NT GEMM, 128x128 tile, BK=32, 256 thr (4 waves, 64x64/wave) ----------
// R5 measured-best structure (60.5 us/dispatch): 2x2 wave grid -> ds_read amplification
// A x2, B x2; 128^2 tile, dbuf, swizzled staging; grid 512 = 2 blocks/CU.
// MODE 0: C = A@B (S = M^2); ITER0: C *= invtr^2; CSUM=1 -> colsum
// MODE 1: C = 0.25(9*M*sc - 6*S + (A@B)*sc), sc = ITER0? invtr : 1; CSUM=2 -> vacc += vin.C
// MODE 3: C = (A@B)*cscale (cov); fused trace; CSUM=1 -> colsum(cov)
template<int MODE, int CSUM, int ITER0>
__global__ __launch_bounds__(256, 2) void gemm_full(
        const unsigned short* __restrict__ Ah, const unsigned short* __restrict__ Al,
        const unsigned short* __restrict__ Bh, const unsigned short* __restrict__ Bl,
        const unsigned short* __restrict__ Mh, const unsigned short* __restrict__ Ml,
        const unsigned short* __restrict__ Sh, const unsigned short* __restrict__ Sl,
        unsigned short* __restrict__ Ch, unsigned short* __restrict__ Cl,
        float* __restrict__ trp, float* __restrict__ csum, const float* __restrict__ vin,
        int K, int lda, float cscale) {
    __shared__ __align__(16) char smem[74240];   // 2x32768 staging | 128*129 f32 tile + colred
    unsigned short* stage = (unsigned short*)smem;
    float* tilef  = (float*)smem;
    float* colred = (float*)(smem + 66048);      // [16][128]

    int bid = blockIdx.x;
    int bz = bid & 31;
    int tt = bid >> 5;
    int by = tt >> 2, bx = tt & 3;

    size_t sAB = (size_t)512 * lda;
    size_t sC  = (size_t)512 * 512;
    const unsigned short* pAh = Ah + (size_t)bz * sAB;
    const unsigned short* pAl = Al + (size_t)bz * sAB;
    const unsigned short* pBh = Bh + (size_t)bz * sAB;
    const unsigned short* pBl = Bl + (size_t)bz * sAB;

    int tid = threadIdx.x;
    int w = tid >> 6, l = tid & 63;          // 4 waves
    int rb0 = by * 128, cb0 = bx * 128;

    // staging: wave w stages plane w (0:Ah 1:Al 2:Bh 3:Bl), 8 units of 1KB each.
    // slot s = u*64 + l: row r = s>>2, k-slot g = (s&3)^((r>>1)&3) (pre-swizzled global
    // src, linear LDS dest = wave-uniform base + lane*16B).
    const unsigned short* gp = (w == 0) ? pAh : (w == 1) ? pAl : (w == 2) ? pBh : pBl;
    int rowbase = (w < 2) ? rb0 : cb0;
    size_t goff[8];
    int ldsoff[8];
    #pragma unroll
    for (int q = 0; q < 8; ++q) {
        int s0 = q * 64;                     // wave-uniform slot base within plane
        int s = s0 + l;
        int r = s >> 2, g = (s & 3) ^ ((r >> 1) & 3);
        goff[q] = (size_t)(rowbase + r) * lda + g * 8;
        ldsoff[q] = w * 4096 + s0 * 8;       // shorts, wave-uniform
    }

    f4 zero4 = {0.f, 0.f, 0.f, 0.f};
    f4 acc[4][4];
    #pragma unroll
    for (int i = 0; i < 4; ++i)
        #pragma unroll
        for (int j = 0; j < 4; ++j) acc[i][j] = zero4;

    int fr = l & 15, quad = l >> 4;
    int sw = quad ^ ((fr >> 1) & 3);
    int wr = w >> 1, wc = w & 1;             // wave tile: rows [wr*64,+64), cols [wc*64,+64)
    int NK = K >> 5;

    {   // prologue: stage chunk 0 into buf 0
        #pragma unroll
        for (int q = 0; q < 8; ++q) async16(gp + goff[q], stage + ldsoff[q]);
    }
    for (int ki = 0; ki < NK; ++ki) {
        __syncthreads();                     // drains buf[ki&1] (vmcnt0 + barrier)
        if (ki + 1 < NK) {
            int k0 = (ki + 1) << 5;
            unsigned short* sb2 = stage + ((ki + 1) & 1) * 16384;
            #pragma unroll
            for (int q = 0; q < 8; ++q) async16(gp + goff[q] + k0, sb2 + ldsoff[q]);
        }
        const unsigned short* sb = stage + (ki & 1) * 16384;
        bf8 ah[4], alo[4], bh[4], blo[4];
        #pragma unroll
        for (int i = 0; i < 4; ++i) {
            int oa = ((wr * 64 + i * 16 + fr) * 4 + sw) * 8;
            ah[i]  = *(const bf8*)&sb[0 * 4096 + oa];
            alo[i] = *(const bf8*)&sb[1 * 4096 + oa];
        }
        #pragma unroll
        for (int j = 0; j < 4; ++j) {
            int ob = ((wc * 64 + j * 16 + fr) * 4 + sw) * 8;
            bh[j]  = *(const bf8*)&sb[2 * 4096 + ob];
            blo[j] = *(const bf8*)&sb[3 * 4096 + ob];
        }
        #pragma unroll
        for (int i = 0; i < 4; ++i)
            #pragma unroll
            for (int j = 0; j < 4; ++j) {
                acc[i][j] = __builtin_amdgcn_mfma_f32_16x16x32_bf16(ah[i],  bh[j],  acc[i][j], 0, 0, 0);
                acc[i][j] = __builtin_amdgcn_mfma_f32_16x16x32_bf16(ah[i],  blo[j], acc[i][j], 0, 0, 0);
                acc[i][j] = __builtin_amdgcn_mfma_f32_16x16x32_bf16(alo[i], bh[j],  acc[i][j], 0, 0, 0);
            }
    }

    // ---- epilogue: acc -> f32 LDS tile [128][129] ----
    __syncthreads();
    #pragma unroll
    for (int i = 0; i < 4; ++i) {
        int rloc = wr * 64 + i * 16 + quad * 4;
        #pragma unroll
        for (int j = 0; j < 4; ++j) {
            int cloc = wc * 64 + j * 16 + fr;
            #pragma unroll
            for (int r = 0; r < 4; ++r) tilef[(rloc + r) * 129 + cloc] = acc[i][j][r];
        }
    }
    __syncthreads();

    float invtr_e = 1.0f;
    if ((MODE == 0 || MODE == 1) && ITER0) invtr_e = 1.0f / trp[bz];
    const float sc_g = (MODE == 3) ? cscale
                      : (MODE == 0 ? (ITER0 ? invtr_e * invtr_e : 1.0f)
                                   : (ITER0 ? invtr_e : 1.0f));

    unsigned short* qCh = Ch + (size_t)bz * sC;
    unsigned short* qCl = Cl + (size_t)bz * sC;
    const unsigned short* qMh = (MODE == 1) ? Mh + (size_t)bz * sC : nullptr;
    const unsigned short* qMl = (MODE == 1) ? Ml + (size_t)bz * sC : nullptr;
    const unsigned short* qSh = (MODE == 1) ? Sh + (size_t)bz * sC : nullptr;
    const unsigned short* qSl = (MODE == 1) ? Sl + (size_t)bz * sC : nullptr;

    int lr = tid >> 4, lc0 = (tid & 15) * 8;     // lr 0..15
    float cp[8] = {0.f, 0.f, 0.f, 0.f, 0.f, 0.f, 0.f, 0.f};
    #pragma unroll
    for (int p = 0; p < 8; ++p) {
        int row = lr + p * 16;                   // 0..127
        int grow = rb0 + row, gcol = cb0 + lc0;
        float vv[8];
        #pragma unroll
        for (int k = 0; k < 8; ++k) vv[k] = tilef[row * 129 + lc0 + k];
        size_t gaddr = (size_t)grow * 512 + gcol;
        if (MODE == 3 || MODE == 0) {
            #pragma unroll
            for (int k = 0; k < 8; ++k) vv[k] *= sc_g;
        }
        if (MODE == 1) {
            uint4 mh = *(const uint4*)&qMh[gaddr], ml = *(const uint4*)&qMl[gaddr];
            uint4 sh = *(const uint4*)&qSh[gaddr], sl = *(const uint4*)&qSl[gaddr];
            const unsigned int* mhp = (const unsigned int*)&mh; const unsigned int* mlp = (const unsigned int*)&ml;
            const unsigned int* shp = (const unsigned int*)&sh; const unsigned int* slp = (const unsigned int*)&sl;
            #pragma unroll
            for (int k = 0; k < 8; ++k) {
                unsigned int hm = mhp[k >> 1], lm = mlp[k >> 1], hs = shp[k >> 1], ls = slp[k >> 1];
                float mval = bf2f((unsigned short)((k & 1) ? (hm >> 16) : (hm & 0xffffu)))
                           + bf2f((unsigned short)((k & 1) ? (lm >> 16) : (lm & 0xffffu)));
                float sval = bf2f((unsigned short)((k & 1) ? (hs >> 16) : (hs & 0xffffu)))
                           + bf2f((unsigned short)((k & 1) ? (ls >> 16) : (ls & 0xffffu)));
                vv[k] = 0.25f * (9.0f * mval * sc_g - 6.0f * sval + vv[k] * sc_g);
            }
        }
        unsigned short h[8], lo[8];
        #pragma unroll
        for (int k = 0; k < 8; ++k) split_bf(vv[k], h[k], lo[k]);
        uint4 uh, ul;
        uh.x = packbf(h[0], h[1]); uh.y = packbf(h[2], h[3]); uh.z = packbf(h[4], h[5]); uh.w = packbf(h[6], h[7]);
        ul.x = packbf(lo[0], lo[1]); ul.y = packbf(lo[2], lo[3]); ul.z = packbf(lo[4], lo[5]); ul.w = packbf(lo[6], lo[7]);
        *(uint4*)&qCh[gaddr] = uh;
        *(uint4*)&qCl[gaddr] = ul;
        if (MODE == 3 && bx == by) {            // trace (diag tiles)
            int d = row - lc0;
            if (d >= 0 && d < 8) atomicAdd(&trp[bz], vv[d]);
        }
        if (CSUM == 1) {
            #pragma unroll
            for (int k = 0; k < 8; ++k) cp[k] += vv[k];
        } else if (CSUM == 2) {
            float wgt = vin[bz * 512 + grow];
            #pragma unroll
            for (int k = 0; k < 8; ++k) cp[k] += wgt * vv[k];
        }
    }
    if (CSUM) {     // 16 row-groups x 128 cols -> 1 atomic/col
        __syncthreads();
        #pragma unroll
        for (int k = 0; k < 8; ++k) colred[lr * 128 + lc0 + k] = cp[k];
        __syncthreads();
        if (tid < 128) {
            float s = 0.f;
            #pragma unroll
            for (int r = 0; r < 16; ++r) s += colred[r * 128 + tid];
            atomicAdd(&csum[bz * 512 + cb0 + tid], s);
        }
    }
}

// ---------- v1 = 1.5*c0/tr - 0.5*c1 ----------
__global__ __launch_bounds__(512) void vkernA(const float* __restrict__ c0,
        const float* __restrict__ c1, const float* __restrict__ tr, float* __restrict__ v) {
    int b = blockIdx.x, c = threadIdx.x;
    float invt = 1.0f / tr[b];
    v[b * 512 + c] = 1.5f * c0[b * 512 + c] * invt - 0.5f * c1[b * 512 + c];
}

// ---------- v = 1.5*v - 0.5*vacc ----------
__global__ __launch_bounds__(512) void vkernB(const float* __restrict__ vacc, float* __restrict__ v) {
    int i = blockIdx.x * 512 + threadIdx.x;
    v[i] = 1.5f * v[i] - 0.5f * vacc[i];
}

// ---------- cooperative GEMV-chain tail + final scale ----------
// 12 chained GEMVs against M2 (grid.sync between steps), then out = x*v5/512*sqrt(tr).
// Slot ids = VEC indices: 3:vacc1 4:v2 5:v3 6:v4 7:r1 8:r2 9..11:p 12..14:q 15..17:s 18..20:u
__constant__ int   T_a0[12] = {4, 9, 10, 5, 12, 13, 12, 15, 16, 15, 18, 19};
__constant__ int   T_a1[12] = {3, -1, -1, 9, -1, -1, 13, -1, -1, 16, -1, -1};
__constant__ int   T_a2[12] = {-1, -1, -1, 10, -1, -1, 14, -1, -1, 17, -1, -1};
__constant__ int   T_a3[12] = {-1, -1, -1, 11, -1, -1, -1, -1, -1, -1, -1, -1};
__constant__ float T_k0[12] = {1.5f, 1.f, 1.f, 1.5f, 1.f, 1.f, 2.25f, 1.f, 1.f, 2.25f, 1.f, 1.f};
__constant__ float T_k1[12] = {-0.5f, 0.f, 0.f, -1.125f, 0.f, 0.f, -1.5f, 0.f, 0.f, -1.5f, 0.f, 0.f};
__constant__ float T_k2[12] = {0.f, 0.f, 0.f, 0.75f, 0.f, 0.f, 0.25f, 0.f, 0.f, 0.25f, 0.f, 0.f};
__constant__ float T_k3[12] = {0.f, 0.f, 0.f, -0.125f, 0.f, 0.f, 0.f, 0.f, 0.f, 0.f, 0.f, 0.f};
__constant__ int   T_wst[12] = {5, -1, -1, 6, -1, -1, 7, -1, -1, 8, -1, -1};
__constant__ int   T_out[12] = {9, 10, 11, 12, 13, 14, 15, 16, 17, 18, 19, 20};

__global__ __launch_bounds__(512) void tail_chain(
        const unsigned short* __restrict__ Mh, const unsigned short* __restrict__ Ml,
        float* __restrict__ vbase, const float* __restrict__ x,
        float* __restrict__ out, const float* __restrict__ tr) {
    cg::grid_group grid = cg::this_grid();
    __shared__ float w[512];
    __shared__ __align__(16) float red[4][512];
    int b  = blockIdx.x & 31;
    int rc = blockIdx.x >> 5;                  // 0..15
    int t  = threadIdx.x;
    for (int step = 0; step < 12; ++step) {
        float wv = T_k0[step] * vbase[(size_t)T_a0[step] * 16384 + b * 512 + t];
        int a1 = T_a1[step]; if (a1 >= 0) wv += T_k1[step] * vbase[(size_t)a1 * 16384 + b * 512 + t];
        int a2 = T_a2[step]; if (a2 >= 0) wv += T_k2[step] * vbase[(size_t)a2 * 16384 + b * 512 + t];
        int a3 = T_a3[step]; if (a3 >= 0) wv += T_k3[step] * vbase[(size_t)a3 * 16384 + b * 512 + t];
        w[t] = wv;
        int wsi = T_wst[step];
        if (wsi >= 0 && rc == 0) vbase[(size_t)wsi * 16384 + b * 512 + t] = wv;
        __syncthreads();
        int rg = t >> 7, ct = t & 127;         // 4 row-groups x 128 col-threads (4 cols each)
        int row0 = rc * 32 + rg * 8;
        const unsigned short* ph = Mh + ((size_t)b * 512 + row0) * 512 + ct * 4;
        const unsigned short* pl = Ml + ((size_t)b * 512 + row0) * 512 + ct * 4;
        float4 acc = {0.f, 0.f, 0.f, 0.f};
        #pragma unroll
        for (int r = 0; r < 8; ++r) {
            ushort4 h = *(const ushort4*)(ph + (size_t)r * 512);
            ushort4 lo = *(const ushort4*)(pl + (size_t)r * 512);
            float wr = w[row0 + r];
            acc.x += wr * (bf2f(h.x) + bf2f(lo.x));
            acc.y += wr * (bf2f(h.y) + bf2f(lo.y));
            acc.z += wr * (bf2f(h.z) + bf2f(lo.z));
            acc.w += wr * (bf2f(h.w) + bf2f(lo.w));
        }
        *(float4*)&red[rg][ct * 4] = acc;
        __syncthreads();
        float s = red[0][t] + red[1][t] + red[2][t] + red[3][t];
        atomicAdd(&vbase[(size_t)T_out[step] * 16384 + b * 512 + t], s);
        __syncthreads();
        grid.sync();                           // out slot complete before next step reads it
    }
    // final scale: out = x * v5/512 * sqrt(tr); v5 = 1.5v4 -1.125r1 +0.75r2 -0.28125u1 +0.1875u2 -0.03125u3
    const float* v4 = vbase + (size_t)6 * 16384;
    const float* r1 = vbase + (size_t)7 * 16384;
    const float* r2 = vbase + (size_t)8 * 16384;
    const float* u1 = vbase + (size_t)18 * 16384;
    const float* u2 = vbase + (size_t)19 * 16384;
    const float* u3 = vbase + (size_t)20 * 16384;
    size_t nthr = (size_t)gridDim.x * blockDim.x;
    size_t gtid = (size_t)blockIdx.x * blockDim.x + threadIdx.x;
    const size_t N4 = (size_t)32 * 512 * 196;  // float4 count
    for (size_t i = gtid; i < N4; i += nthr) {
        size_t ch = i / 196;
        int bb = (int)(ch >> 9);
        float v5 = 1.5f * v4[ch] - 1.125f * r1[ch] + 0.75f * r2[ch]
                 - 0.28125f * u1[ch] + 0.1875f * u2[ch] - 0.03125f * u3[ch];
        float sc = v5 * (1.0f / 512.0f) * sqrtf(tr[bb]);
        float4 vv = ((const float4*)x)[i];
        vv.x *= sc; vv.y *= sc; vv.z *= sc; vv.w *= sc;
        ((float4*)out)[i] = vv;
    }
}

extern "C" void kernel_launch(void* const* d_in, const int* in_sizes, int n_in,
                              void* d_out, int out_size, void* d_ws, size_t ws_size,
                              hipStream_t stream) {
    const float* x = (const float*)d_in[0];
    float* out = (float*)d_out;
    char* ws = (char*)d_ws;

    const size_t PLANE  = (size_t)32 * 512 * 512 * 2;   // 16.78 MB bf16 plane
    const size_t XPLANE = (size_t)32 * 512 * 800 * 2;   // 26.21 MB padded Xc plane
    const size_t SMALL  = (size_t)(2 << 20);            // small-vector region

    float* tr = (float*)ws;                              // 32 f (atomic)
    #define VEC(i) ((float*)(ws + 4096 + (size_t)(i) * 65536))
    float* c0    = VEC(0);  float* c1    = VEC(1);
    float* vacc0 = VEC(2);  float* vacc1 = VEC(3);
    float* v     = VEC(4);                               // evolving v1,v2

    char* big = ws + SMALL;
    unsigned short* Ah = (unsigned short*)(big);                 // cov/M ping
    unsigned short* Al = (unsigned short*)(big + PLANE);
    char* R0 = big + 2 * PLANE;
    unsigned short* Xh = (unsigned short*)(R0);                  // dead after cov
    unsigned short* Xl = (unsigned short*)(R0 + XPLANE);
    unsigned short* Sh = (unsigned short*)(R0);                  // S = M^2 (overlaps X)
    unsigned short* Sl = (unsigned short*)(R0 + PLANE);
    size_t need = SMALL + 2 * PLANE + 2 * XPLANE + 2 * PLANE;
    unsigned short *Bh, *Bl;                                      // M pong
    if (ws_size >= need) {
        Bh = (unsigned short*)(R0 + 2 * XPLANE);
        Bl = (unsigned short*)(R0 + 2 * XPLANE + PLANE);
    } else {                                              // d_out scratch (51.4 MB >= 33.5 MB)
        Bh = (unsigned short*)out;
        Bl = (unsigned short*)out + (size_t)32 * 512 * 512;
    }

    hipMemsetAsync(ws, 0, 4096 + 21 * 65536, stream);    // zero tr + all vector slots (atomics)

    // 1) center + split
    center_convert<<<32 * 512, 256, 0, stream>>>(x, Xh, Xl);
    // 2) cov = Xc@Xc^T/784; fused trace + colsum(cov)->c0
    gemm_full<3, 1, 0><<<512, 256, 0, stream>>>(Xh, Xl, Xh, Xl, nullptr, nullptr, nullptr, nullptr,
                                                Ah, Al, tr, c0, nullptr, 800, 800, 1.0f / 784.0f);
    // 3) S0 = cov^2/tr^2 ; fused colsum(S0)->c1
    gemm_full<0, 1, 1><<<512, 256, 0, stream>>>(Ah, Al, Ah, Al, nullptr, nullptr, nullptr, nullptr,
                                                Sh, Sl, tr, c1, nullptr, 512, 512, 1.0f);
    // 4) v1 = 1.5*c0/tr - 0.5*c1
    vkernA<<<32, 512, 0, stream>>>(c0, c1, tr, v);
    // 5) M1 = 0.25(9*cov/tr - 6*S0 + cov@S0/tr) -> B ; fused vacc0 = v1 @ M1
    gemm_full<1, 2, 1><<<512, 256, 0, stream>>>(Ah, Al, Sh, Sl, Ah, Al, Sh, Sl,
                                                Bh, Bl, tr, vacc0, v, 512, 512, 1.0f);
    // 6) v2 = 1.5*v1 - 0.5*vacc0
    vkernB<<<32, 512, 0, stream>>>(vacc0, v);
    // 7) S1 = M1^2
    gemm_full<0, 0, 0><<<512, 256, 0, stream>>>(Bh, Bl, Bh, Bl, nullptr, nullptr, nullptr, nullptr,
                                                Sh, Sl, tr, nullptr, nullptr, 512, 512, 1.0f);
    // 8) M2 = 0.25(9*M1 - 6*S1 + M1@S1) -> A ; fused vacc1 = v2 @ M2
    gemm_full<1, 2, 0><<<512, 256, 0, stream>>>(Bh, Bl, Sh, Sl, Bh, Bl, Sh, Sl,
                                                Ah, Al, tr, vacc1, v, 512, 512, 1.0f);

    // 9+10) cooperative tail: 12 GEMVs vs M2 (M3,M4 never materialized) + final scale.
    //    g(x) = 0.25(9x - 6x^2 + x^3); x@g(M) = 2.25(xM) - 1.5(xM^2) + 0.25(xM^3).
    {
        float* vbase = VEC(0);
        const unsigned short* M2h = Ah; const unsigned short* M2l = Al;
        void* kargs[] = {(void*)&M2h, (void*)&M2l, (void*)&vbase,
                         (void*)&x, (void*)&out, (void*)&tr};
        hipLaunchCooperativeKernel((void*)tail_chain, dim3(512), dim3(512), kargs, 0, stream);
    }
    #undef VEC
}

// Round 9
// 391.874 us; speedup vs baseline: 2.5744x; 2.5744x over previous
//
#include <hip/hip_runtime.h>
#include <math.h>

typedef short bf8 __attribute__((ext_vector_type(8)));   // 8 bf16 = 4 VGPRs
typedef float f4 __attribute__((ext_vector_type(4)));

__device__ inline unsigned short f2bf(float f) {          // RNE f32 -> bf16
    unsigned int u = __float_as_uint(f);
    u = u + 0x7fffu + ((u >> 16) & 1u);
    return (unsigned short)(u >> 16);
}
__device__ inline float bf2f(unsigned short h) {
    return __uint_as_float(((unsigned int)h) << 16);
}
__device__ inline void split_bf(float v, unsigned short& h, unsigned short& l) {
    h = f2bf(v);
    l = f2bf(v - bf2f(h));
}
__device__ inline unsigned int packbf(unsigned short a, unsigned short b) {
    return (unsigned int)a | ((unsigned int)b << 16);
}
__device__ inline void async16(const void* g, void* l) {
    __builtin_amdgcn_global_load_lds(
        (const __attribute__((address_space(1))) unsigned int*)g,
        (__attribute__((address_space(3))) unsigned int*)l, 16, 0, 0);
}

// ---------- fuse row-mean + center + bf16 hi/lo split (K padded 784->800 with zeros) ----------
__global__ __launch_bounds__(256) void center_convert(const float* __restrict__ x,
        unsigned short* __restrict__ Xh, unsigned short* __restrict__ Xl) {
    int row = blockIdx.x;                       // b*512 + c
    const float* xr = x + (size_t)row * 784;
    int t = threadIdx.x;
    float4 vv = {0.f, 0.f, 0.f, 0.f};
    if (t < 196) vv = *(const float4*)(xr + t * 4);
    float s = vv.x + vv.y + vv.z + vv.w;
    #pragma unroll
    for (int o = 32; o > 0; o >>= 1) s += __shfl_down(s, o, 64);
    __shared__ float red[4];
    int lane = t & 63, wv = t >> 6;
    if (lane == 0) red[wv] = s;
    __syncthreads();
    float m = (red[0] + red[1] + red[2] + red[3]) * (1.0f / 784.0f);
    if (t < 200) {
        ushort4 hh = {0, 0, 0, 0}, ll = {0, 0, 0, 0};
        if (t < 196) {
            split_bf(vv.x - m, hh.x, ll.x);
            split_bf(vv.y - m, hh.y, ll.y);
            split_bf(vv.z - m, hh.z, ll.z);
            split_bf(vv.w - m, hh.w, ll.w);
        }
        *(ushort4*)&Xh[(size_t)row * 800 + t * 4] = hh;
        *(ushort4*)&Xl[(size_t)row * 800 + t * 4] = ll;
    }
}

// ---------- full-grid bf16x3 NT GEMM, 128x128 tile, BK=32, 256 thr (4 waves, 64x64/wave) ----------
// R5 measured-best structure (60.5 us/dispatch) + BATCH-MAJOR XCD MAPPING:
// bid = (bz&7) | (tile<<3) | ((bz>>3)<<7)  =>  XCD x (= bid%8) hosts ALL 16 tiles of
// batches {x, x+8} concurrently; per-XCD L2 working set = those batches' full A/B
// matrices (2-4 MB, L2-fits) instead of 4 interleaved batches' panels (~6 MB thrash).
// Staging then L2-hits; L3/fabric traffic drops ~4x.
// MODE 0: C = A@B (S = M^2); ITER0: C *= invtr^2; CSUM=1 -> colsum
// MODE 1: C = 0.25(9*M*sc - 6*S + (A@B)*sc), sc = ITER0? invtr : 1; CSUM=2 -> vacc += vin.C
// MODE 3: C = (A@B)*cscale (cov); fused trace; CSUM=1 -> colsum(cov)
template<int MODE, int CSUM, int ITER0>
__global__ __launch_bounds__(256, 2) void gemm_full(
        const unsigned short* __restrict__ Ah, const unsigned short* __restrict__ Al,
        const unsigned short* __restrict__ Bh, const unsigned short* __restrict__ Bl,
        const unsigned short* __restrict__ Mh, const unsigned short* __restrict__ Ml,
        const unsigned short* __restrict__ Sh, const unsigned short* __restrict__ Sl,
        unsigned short* __restrict__ Ch, unsigned short* __restrict__ Cl,
        float* __restrict__ trp, float* __restrict__ csum, const float* __restrict__ vin,
        int K, int lda, float cscale) {
    __shared__ __align__(16) char smem[74240];   // 2x32768 staging | 128*129 f32 tile + colred
    unsigned short* stage = (unsigned short*)smem;
    float* tilef  = (float*)smem;
    float* colred = (float*)(smem + 66048);      // [16][128]

    int bid = blockIdx.x;
    int bz = (bid & 7) + ((bid >> 7) << 3);  // batch-major: bz = bid&7 + 8*(bid>>7)
    int tt = (bid >> 3) & 15;                // tile index 0..15
    int by = tt >> 2, bx = tt & 3;

    size_t sAB = (size_t)512 * lda;
    size_t sC  = (size_t)512 * 512;
    const unsigned short* pAh = Ah + (size_t)bz * sAB;
    const unsigned short* pAl = Al + (size_t)bz * sAB;
    const unsigned short* pBh = Bh + (size_t)bz * sAB;
    const unsigned short* pBl = Bl + (size_t)bz * sAB;

    int tid = threadIdx.x;
    int w = tid >> 6, l = tid & 63;          // 4 waves
    int rb0 = by * 128, cb0 = bx * 128;

    // staging: wave w stages plane w (0:Ah 1:Al 2:Bh 3:Bl), 8 units of 1KB each.
    // slot s = u*64 + l: row r = s>>2, k-slot g = (s&3)^((r>>1)&3) (pre-swizzled global
    // src, linear LDS dest = wave-uniform base + lane*16B).
    const unsigned short* gp = (w == 0) ? pAh : (w == 1) ? pAl : (w == 2) ? pBh : pBl;
    int rowbase = (w < 2) ? rb0 : cb0;
    size_t goff[8];
    int ldsoff[8];
    #pragma unroll
    for (int q = 0; q < 8; ++q) {
        int s0 = q * 64;                     // wave-uniform slot base within plane
        int s = s0 + l;
        int r = s >> 2, g = (s & 3) ^ ((r >> 1) & 3);
        goff[q] = (size_t)(rowbase + r) * lda + g * 8;
        ldsoff[q] = w * 4096 + s0 * 8;       // shorts, wave-uniform
    }

    f4 zero4 = {0.f, 0.f, 0.f, 0.f};
    f4 acc[4][4];
    #pragma unroll
    for (int i = 0; i < 4; ++i)
        #pragma unroll
        for (int j = 0; j < 4; ++j) acc[i][j] = zero4;

    int fr = l & 15, quad = l >> 4;
    int sw = quad ^ ((fr >> 1) & 3);
    int wr = w >> 1, wc = w & 1;             // wave tile: rows [wr*64,+64), cols [wc*64,+64)
    int NK = K >> 5;

    {   // prologue: stage chunk 0 into buf 0
        #pragma unroll
        for (int q = 0; q < 8; ++q) async16(gp + goff[q], stage + ldsoff[q]);
    }
    for (int ki = 0; ki < NK; ++ki) {
        __syncthreads();                     // drains buf[ki&1] (vmcnt0 + barrier)
        if (ki + 1 < NK) {
            int k0 = (ki + 1) << 5;
            unsigned short* sb2 = stage + ((ki + 1) & 1) * 16384;
            #pragma unroll
            for (int q = 0; q < 8; ++q) async16(gp + goff[q] + k0, sb2 + ldsoff[q]);
        }
        const unsigned short* sb = stage + (ki & 1) * 16384;
        bf8 ah[4], alo[4], bh[4], blo[4];
        #pragma unroll
        for (int i = 0; i < 4; ++i) {
            int oa = ((wr * 64 + i * 16 + fr) * 4 + sw) * 8;
            ah[i]  = *(const bf8*)&sb[0 * 4096 + oa];
            alo[i] = *(const bf8*)&sb[1 * 4096 + oa];
        }
        #pragma unroll
        for (int j = 0; j < 4; ++j) {
            int ob = ((wc * 64 + j * 16 + fr) * 4 + sw) * 8;
            bh[j]  = *(const bf8*)&sb[2 * 4096 + ob];
            blo[j] = *(const bf8*)&sb[3 * 4096 + ob];
        }
        #pragma unroll
        for (int i = 0; i < 4; ++i)
            #pragma unroll
            for (int j = 0; j < 4; ++j) {
                acc[i][j] = __builtin_amdgcn_mfma_f32_16x16x32_bf16(ah[i],  bh[j],  acc[i][j], 0, 0, 0);
                acc[i][j] = __builtin_amdgcn_mfma_f32_16x16x32_bf16(ah[i],  blo[j], acc[i][j], 0, 0, 0);
                acc[i][j] = __builtin_amdgcn_mfma_f32_16x16x32_bf16(alo[i], bh[j],  acc[i][j], 0, 0, 0);
            }
    }

    // ---- epilogue: acc -> f32 LDS tile [128][129] ----
    __syncthreads();
    #pragma unroll
    for (int i = 0; i < 4; ++i) {
        int rloc = wr * 64 + i * 16 + quad * 4;
        #pragma unroll
        for (int j = 0; j < 4; ++j) {
            int cloc = wc * 64 + j * 16 + fr;
            #pragma unroll
            for (int r = 0; r < 4; ++r) tilef[(rloc + r) * 129 + cloc] = acc[i][j][r];
        }
    }
    __syncthreads();

    float invtr_e = 1.0f;
    if ((MODE == 0 || MODE == 1) && ITER0) invtr_e = 1.0f / trp[bz];
    const float sc_g = (MODE == 3) ? cscale
                      : (MODE == 0 ? (ITER0 ? invtr_e * invtr_e : 1.0f)
                                   : (ITER0 ? invtr_e : 1.0f));

    unsigned short* qCh = Ch + (size_t)bz * sC;
    unsigned short* qCl = Cl + (size_t)bz * sC;
    const unsigned short* qMh = (MODE == 1) ? Mh + (size_t)bz * sC : nullptr;
    const unsigned short* qMl = (MODE == 1) ? Ml + (size_t)bz * sC : nullptr;
    const unsigned short* qSh = (MODE == 1) ? Sh + (size_t)bz * sC : nullptr;
    const unsigned short* qSl = (MODE == 1) ? Sl + (size_t)bz * sC : nullptr;

    int lr = tid >> 4, lc0 = (tid & 15) * 8;     // lr 0..15
    float cp[8] = {0.f, 0.f, 0.f, 0.f, 0.f, 0.f, 0.f, 0.f};
    #pragma unroll
    for (int p = 0; p < 8; ++p) {
        int row = lr + p * 16;                   // 0..127
        int grow = rb0 + row, gcol = cb0 + lc0;
        float vv[8];
        #pragma unroll
        for (int k = 0; k < 8; ++k) vv[k] = tilef[row * 129 + lc0 + k];
        size_t gaddr = (size_t)grow * 512 + gcol;
        if (MODE == 3 || MODE == 0) {
            #pragma unroll
            for (int k = 0; k < 8; ++k) vv[k] *= sc_g;
        }
        if (MODE == 1) {
            uint4 mh = *(const uint4*)&qMh[gaddr], ml = *(const uint4*)&qMl[gaddr];
            uint4 sh = *(const uint4*)&qSh[gaddr], sl = *(const uint4*)&qSl[gaddr];
            const unsigned int* mhp = (const unsigned int*)&mh; const unsigned int* mlp = (const unsigned int*)&ml;
            const unsigned int* shp = (const unsigned int*)&sh; const unsigned int* slp = (const unsigned int*)&sl;
            #pragma unroll
            for (int k = 0; k < 8; ++k) {
                unsigned int hm = mhp[k >> 1], lm = mlp[k >> 1], hs = shp[k >> 1], ls = slp[k >> 1];
                float mval = bf2f((unsigned short)((k & 1) ? (hm >> 16) : (hm & 0xffffu)))
                           + bf2f((unsigned short)((k & 1) ? (lm >> 16) : (lm & 0xffffu)));
                float sval = bf2f((unsigned short)((k & 1) ? (hs >> 16) : (hs & 0xffffu)))
                           + bf2f((unsigned short)((k & 1) ? (ls >> 16) : (ls & 0xffffu)));
                vv[k] = 0.25f * (9.0f * mval * sc_g - 6.0f * sval + vv[k] * sc_g);
            }
        }
        unsigned short h[8], lo[8];
        #pragma unroll
        for (int k = 0; k < 8; ++k) split_bf(vv[k], h[k], lo[k]);
        uint4 uh, ul;
        uh.x = packbf(h[0], h[1]); uh.y = packbf(h[2], h[3]); uh.z = packbf(h[4], h[5]); uh.w = packbf(h[6], h[7]);
        ul.x = packbf(lo[0], lo[1]); ul.y = packbf(lo[2], lo[3]); ul.z = packbf(lo[4], lo[5]); ul.w = packbf(lo[6], lo[7]);
        *(uint4*)&qCh[gaddr] = uh;
        *(uint4*)&qCl[gaddr] = ul;
        if (MODE == 3 && bx == by) {            // trace (diag tiles)
            int d = row - lc0;
            if (d >= 0 && d < 8) atomicAdd(&trp[bz], vv[d]);
        }
        if (CSUM == 1) {
            #pragma unroll
            for (int k = 0; k < 8; ++k) cp[k] += vv[k];
        } else if (CSUM == 2) {
            float wgt = vin[bz * 512 + grow];
            #pragma unroll
            for (int k = 0; k < 8; ++k) cp[k] += wgt * vv[k];
        }
    }
    if (CSUM) {     // 16 row-groups x 128 cols -> 1 atomic/col
        __syncthreads();
        #pragma unroll
        for (int k = 0; k < 8; ++k) colred[lr * 128 + lc0 + k] = cp[k];
        __syncthreads();
        if (tid < 128) {
            float s = 0.f;
            #pragma unroll
            for (int r = 0; r < 16; ++r) s += colred[r * 128 + tid];
            atomicAdd(&csum[bz * 512 + cb0 + tid], s);
        }
    }
}

// ---------- v1 = 1.5*c0/tr - 0.5*c1 ----------
__global__ __launch_bounds__(512) void vkernA(const float* __restrict__ c0,
        const float* __restrict__ c1, const float* __restrict__ tr, float* __restrict__ v) {
    int b = blockIdx.x, c = threadIdx.x;
    float invt = 1.0f / tr[b];
    v[b * 512 + c] = 1.5f * c0[b * 512 + c] * invt - 0.5f * c1[b * 512 + c];
}

// ---------- v = 1.5*v - 0.5*vacc ----------
__global__ __launch_bounds__(512) void vkernB(const float* __restrict__ vacc, float* __restrict__ v) {
    int i = blockIdx.x * 512 + threadIdx.x;
    v[i] = 1.5f * v[i] - 0.5f * vacc[i];
}

// ---------- GEMV: out[b,:] (+)= w[b,:] @ M[b,:,:], M = bf16 hi+lo planes ----------
// batch-major XCD mapping: b = (bid&7)+8*(bid>>7), rc = (bid>>3)&15  (per-XCD M2 set 4MB)
__global__ __launch_bounds__(512) void gemv_ml(
        const unsigned short* __restrict__ Mh, const unsigned short* __restrict__ Ml,
        const float* __restrict__ a0, const float* __restrict__ a1,
        const float* __restrict__ a2, const float* __restrict__ a3,
        float k0, float k1, float k2, float k3,
        float* __restrict__ wstore, float* __restrict__ out) {
    __shared__ float w[512];
    __shared__ __align__(16) float red[4][512];
    int bid = blockIdx.x;
    int b  = (bid & 7) + ((bid >> 7) << 3);
    int rc = (bid >> 3) & 15;                  // 0..15
    int t  = threadIdx.x;
    float wv = k0 * a0[b * 512 + t];
    if (a1) wv += k1 * a1[b * 512 + t];
    if (a2) wv += k2 * a2[b * 512 + t];
    if (a3) wv += k3 * a3[b * 512 + t];
    w[t] = wv;
    if (wstore != nullptr && rc == 0) wstore[b * 512 + t] = wv;
    __syncthreads();
    int rg = t >> 7, ct = t & 127;             // 4 row-groups x 128 col-threads (4 cols each)
    int row0 = rc * 32 + rg * 8;
    const unsigned short* ph = Mh + ((size_t)b * 512 + row0) * 512 + ct * 4;
    const unsigned short* pl = Ml + ((size_t)b * 512 + row0) * 512 + ct * 4;
    float4 acc = {0.f, 0.f, 0.f, 0.f};
    #pragma unroll
    for (int r = 0; r < 8; ++r) {
        ushort4 h = *(const ushort4*)(ph + (size_t)r * 512);
        ushort4 lo = *(const ushort4*)(pl + (size_t)r * 512);
        float wr = w[row0 + r];
        acc.x += wr * (bf2f(h.x) + bf2f(lo.x));
        acc.y += wr * (bf2f(h.y) + bf2f(lo.y));
        acc.z += wr * (bf2f(h.z) + bf2f(lo.z));
        acc.w += wr * (bf2f(h.w) + bf2f(lo.w));
    }
    *(float4*)&red[rg][ct * 4] = acc;
    __syncthreads();
    float s = red[0][t] + red[1][t] + red[2][t] + red[3][t];
    atomicAdd(&out[b * 512 + t], s);
}

// ---------- out = x * v5[ch]/512*sqrt(tr[b]);  v5 = 1.5v4 -1.125r1 +0.75r2 -0.28125u1 +0.1875u2 -0.03125u3 ----------
__global__ __launch_bounds__(256) void scale_x6(const float* __restrict__ x,
        const float* __restrict__ v4, const float* __restrict__ r1, const float* __restrict__ r2,
        const float* __restrict__ u1, const float* __restrict__ u2, const float* __restrict__ u3,
        const float* __restrict__ tr, float* __restrict__ out) {
    size_t i = (size_t)blockIdx.x * 256 + threadIdx.x;
    size_t ch = i / 196;
    int b = (int)(ch >> 9);
    float v5 = 1.5f * v4[ch] - 1.125f * r1[ch] + 0.75f * r2[ch]
             - 0.28125f * u1[ch] + 0.1875f * u2[ch] - 0.03125f * u3[ch];
    float sc = v5 * (1.0f / 512.0f) * sqrtf(tr[b]);
    float4 vv = ((const float4*)x)[i];
    vv.x *= sc; vv.y *= sc; vv.z *= sc; vv.w *= sc;
    ((float4*)out)[i] = vv;
}

extern "C" void kernel_launch(void* const* d_in, const int* in_sizes, int n_in,
                              void* d_out, int out_size, void* d_ws, size_t ws_size,
                              hipStream_t stream) {
    const float* x = (const float*)d_in[0];
    float* out = (float*)d_out;
    char* ws = (char*)d_ws;

    const size_t PLANE  = (size_t)32 * 512 * 512 * 2;   // 16.78 MB bf16 plane
    const size_t XPLANE = (size_t)32 * 512 * 800 * 2;   // 26.21 MB padded Xc plane
    const size_t SMALL  = (size_t)(2 << 20);            // small-vector region

    float* tr = (float*)ws;                              // 32 f (atomic)
    #define VEC(i) ((float*)(ws + 4096 + (size_t)(i) * 65536))
    float* c0    = VEC(0);  float* c1    = VEC(1);
    float* vacc0 = VEC(2);  float* vacc1 = VEC(3);
    float* v     = VEC(4);                               // evolving v1,v2
    float* v3    = VEC(5);  float* v4    = VEC(6);
    float* r1    = VEC(7);  float* r2    = VEC(8);
    float* p1    = VEC(9);  float* p2    = VEC(10); float* p3 = VEC(11);
    float* q1    = VEC(12); float* q2    = VEC(13); float* q3 = VEC(14);
    float* s1    = VEC(15); float* s2    = VEC(16); float* s3 = VEC(17);
    float* u1    = VEC(18); float* u2    = VEC(19); float* u3 = VEC(20);

    char* big = ws + SMALL;
    unsigned short* Ah = (unsigned short*)(big);                 // cov/M ping
    unsigned short* Al = (unsigned short*)(big + PLANE);
    char* R0 = big + 2 * PLANE;
    unsigned short* Xh = (unsigned short*)(R0);                  // dead after cov
    unsigned short* Xl = (unsigned short*)(R0 + XPLANE);
    unsigned short* Sh = (unsigned short*)(R0);                  // S = M^2 (overlaps X)
    unsigned short* Sl = (unsigned short*)(R0 + PLANE);
    size_t need = SMALL + 2 * PLANE + 2 * XPLANE + 2 * PLANE;
    unsigned short *Bh, *Bl;                                      // M pong
    if (ws_size >= need) {
        Bh = (unsigned short*)(R0 + 2 * XPLANE);
        Bl = (unsigned short*)(R0 + 2 * XPLANE + PLANE);
    } else {                                              // d_out scratch (51.4 MB >= 33.5 MB)
        Bh = (unsigned short*)out;
        Bl = (unsigned short*)out + (size_t)32 * 512 * 512;
    }

    hipMemsetAsync(ws, 0, 4096 + 21 * 65536, stream);    // zero tr + all vector slots (atomics)

    // 1) center + split
    center_convert<<<32 * 512, 256, 0, stream>>>(x, Xh, Xl);
    // 2) cov = Xc@Xc^T/784; fused trace + colsum(cov)->c0
    gemm_full<3, 1, 0><<<512, 256, 0, stream>>>(Xh, Xl, Xh, Xl, nullptr, nullptr, nullptr, nullptr,
                                                Ah, Al, tr, c0, nullptr, 800, 800, 1.0f / 784.0f);
    // 3) S0 = cov^2/tr^2 ; fused colsum(S0)->c1
    gemm_full<0, 1, 1><<<512, 256, 0, stream>>>(Ah, Al, Ah, Al, nullptr, nullptr, nullptr, nullptr,
                                                Sh, Sl, tr, c1, nullptr, 512, 512, 1.0f);
    // 4) v1 = 1.5*c0/tr - 0.5*c1
    vkernA<<<32, 512, 0, stream>>>(c0, c1, tr, v);
    // 5) M1 = 0.25(9*cov/tr - 6*S0 + cov@S0/tr) -> B ; fused vacc0 = v1 @ M1
    gemm_full<1, 2, 1><<<512, 256, 0, stream>>>(Ah, Al, Sh, Sl, Ah, Al, Sh, Sl,
                                                Bh, Bl, tr, vacc0, v, 512, 512, 1.0f);
    // 6) v2 = 1.5*v1 - 0.5*vacc0
    vkernB<<<32, 512, 0, stream>>>(vacc0, v);
    // 7) S1 = M1^2
    gemm_full<0, 0, 0><<<512, 256, 0, stream>>>(Bh, Bl, Bh, Bl, nullptr, nullptr, nullptr, nullptr,
                                                Sh, Sl, tr, nullptr, nullptr, 512, 512, 1.0f);
    // 8) M2 = 0.25(9*M1 - 6*S1 + M1@S1) -> A ; fused vacc1 = v2 @ M2
    gemm_full<1, 2, 0><<<512, 256, 0, stream>>>(Bh, Bl, Sh, Sl, Bh, Bl, Sh, Sl,
                                                Ah, Al, tr, vacc1, v, 512, 512, 1.0f);

    // 9) GEMV tail against M2 (Ah/Al): M3 = g(M2), M4 = g(M3) never materialized.
    //    g(x) = 0.25(9x - 6x^2 + x^3); x@g(M) = 2.25(xM) - 1.5(xM^2) + 0.25(xM^3).
    gemv_ml<<<512, 512, 0, stream>>>(Ah, Al, v,  vacc1, nullptr, nullptr, 1.5f, -0.5f, 0.f, 0.f, v3, p1);
    gemv_ml<<<512, 512, 0, stream>>>(Ah, Al, p1, nullptr, nullptr, nullptr, 1.f, 0.f, 0.f, 0.f, nullptr, p2);
    gemv_ml<<<512, 512, 0, stream>>>(Ah, Al, p2, nullptr, nullptr, nullptr, 1.f, 0.f, 0.f, 0.f, nullptr, p3);
    // v4 = 1.5*v3 - 0.5*(v3@M3) = 1.5v3 -1.125p1 +0.75p2 -0.125p3 ; q-chain: q_k = v4 @ M2^k
    gemv_ml<<<512, 512, 0, stream>>>(Ah, Al, v3, p1, p2, p3, 1.5f, -1.125f, 0.75f, -0.125f, v4, q1);
    gemv_ml<<<512, 512, 0, stream>>>(Ah, Al, q1, nullptr, nullptr, nullptr, 1.f, 0.f, 0.f, 0.f, nullptr, q2);
    gemv_ml<<<512, 512, 0, stream>>>(Ah, Al, q2, nullptr, nullptr, nullptr, 1.f, 0.f, 0.f, 0.f, nullptr, q3);
    // r1 = v4@M3 = 2.25q1 -1.5q2 +0.25q3 ; s-chain: s_k = r1 @ M2^k
    gemv_ml<<<512, 512, 0, stream>>>(Ah, Al, q1, q2, q3, nullptr, 2.25f, -1.5f, 0.25f, 0.f, r1, s1);
    gemv_ml<<<512, 512, 0, stream>>>(Ah, Al, s1, nullptr, nullptr, nullptr, 1.f, 0.f, 0.f, 0.f, nullptr, s2);
    gemv_ml<<<512, 512, 0, stream>>>(Ah, Al, s2, nullptr, nullptr, nullptr, 1.f, 0.f, 0.f, 0.f, nullptr, s3);
    // r2 = v4@M3^2 = r1@M3 = 2.25s1 -1.5s2 +0.25s3 ; u-chain: u_k = r2 @ M2^k
    gemv_ml<<<512, 512, 0, stream>>>(Ah, Al, s1, s2, s3, nullptr, 2.25f, -1.5f, 0.25f, 0.f, r2, u1);
    gemv_ml<<<512, 512, 0, stream>>>(Ah, Al, u1, nullptr, nullptr, nullptr, 1.f, 0.f, 0.f, 0.f, nullptr, u2);
    gemv_ml<<<512, 512, 0, stream>>>(Ah, Al, u2, nullptr, nullptr, nullptr, 1.f, 0.f, 0.f, 0.f, nullptr, u3);

    // 10) out = x * v5/512 * sqrt(tr); v5 combine fused (r3 = 2.25u1 -1.5u2 +0.25u3)
    scale_x6<<<12544, 256, 0, stream>>>(x, v4, r1, r2, u1, u2, u3, tr, out);
    #undef VEC
}